// Round 8
// baseline (218.399 us; speedup 1.0000x reference)
//
#include <hip/hip_runtime.h>

typedef unsigned short ushort_t;
typedef unsigned int uint32;
typedef __bf16 bf16x8 __attribute__((ext_vector_type(8)));
typedef float f32x4 __attribute__((ext_vector_type(4)));
typedef float f4 __attribute__((ext_vector_type(4)));
typedef unsigned short us4 __attribute__((ext_vector_type(4)));

// ---- constants for this problem shape ----
// B=16, QL=1024, KL=1024, QS=512, KS=512, KW=3, PAD=1
// gemm1: M=16384, N=1536, K=512   gemm2 (per b): M=1024, N=1024, K=1536 (3 shifted 512-segs)

__device__ __forceinline__ ushort_t f2bf(float f) {
    uint32 u = __builtin_bit_cast(uint32, f);
    u = (u + 0x7fffu + ((u >> 16) & 1u)) >> 16;  // RNE
    return (ushort_t)u;
}

#define SB0() __builtin_amdgcn_sched_barrier(0)
#define SBAR() __builtin_amdgcn_s_barrier()
#define VMCNT(n) asm volatile("s_waitcnt vmcnt(" #n ")" ::: "memory")
#define LGKM0_SB() do { asm volatile("s_waitcnt lgkmcnt(0)" ::: "memory"); SB0(); } while (0)

#define AS1 __attribute__((address_space(1)))
#define AS3 __attribute__((address_space(3)))

// ---------------- fused prep ----------------
__global__ __launch_bounds__(256) void prep_all(const float* __restrict__ q,
                                                const float* __restrict__ Wb,
                                                const float* __restrict__ bb,
                                                const float* __restrict__ k,
                                                const float* __restrict__ Wk,
                                                const float* __restrict__ bk,
                                                ushort_t* __restrict__ qb,
                                                float* __restrict__ biasw,
                                                ushort_t* __restrict__ kbp,
                                                ushort_t* __restrict__ wkb,
                                                float* __restrict__ bkp) {
    const int tid = threadIdx.x;
    if (blockIdx.x < 4096) {
        const int lane = tid & 63, wid = tid >> 6;
        const int m = blockIdx.x * 4 + wid;
        const float* qrow = q + (size_t)m * 512;

        f4 v0 = *(const f4*)(qrow + lane * 4);
        f4 v1 = *(const f4*)(qrow + 256 + lane * 4);
        f4 w0 = *(const f4*)(Wb + lane * 4);
        f4 w1 = *(const f4*)(Wb + 256 + lane * 4);

        float dot = v0[0]*w0[0] + v0[1]*w0[1] + v0[2]*w0[2] + v0[3]*w0[3]
                  + v1[0]*w1[0] + v1[1]*w1[1] + v1[2]*w1[2] + v1[3]*w1[3];

        us4 o0, o1;
        o0[0]=f2bf(v0[0]); o0[1]=f2bf(v0[1]); o0[2]=f2bf(v0[2]); o0[3]=f2bf(v0[3]);
        o1[0]=f2bf(v1[0]); o1[1]=f2bf(v1[1]); o1[2]=f2bf(v1[2]); o1[3]=f2bf(v1[3]);
        *(us4*)(qb + (size_t)m * 512 + lane * 4) = o0;
        *(us4*)(qb + (size_t)m * 512 + 256 + lane * 4) = o1;

        #pragma unroll
        for (int off = 32; off >= 1; off >>= 1) dot += __shfl_xor(dot, off);
        if (lane == 0) biasw[m] = dot + bb[0];
        return;
    }
    const int gid = (blockIdx.x - 4096) * 256 + tid;
    if (gid < 1536) bkp[gid] = bk[(gid & 511) * 3 + (gid >> 9)];

    const int KG = (16 * 1024 * 512) / 4;
    const int PG = (16 * 2 * 512) / 4;

    if (gid < KG) {
        const int e = gid * 4;
        const int b = e >> 19;
        const int rem = e & ((1 << 19) - 1);
        const int row = rem >> 9, c = rem & 511;
        f4 v = *(const f4*)(k + e);
        us4 o; o[0]=f2bf(v[0]); o[1]=f2bf(v[1]); o[2]=f2bf(v[2]); o[3]=f2bf(v[3]);
        *(us4*)(kbp + ((size_t)b * 1026 + row + 1) * 512 + c) = o;
    } else if (gid < KG + PG) {
        const int p = gid - KG;
        const int b = p >> 8, off = p & 255;
        const int row = (off < 128) ? 0 : 1025;
        const int c = (off & 127) * 4;
        us4 z; z[0]=0; z[1]=0; z[2]=0; z[3]=0;
        *(us4*)(kbp + ((size_t)b * 1026 + row) * 512 + c) = z;
    } else {
        const int w = gid - KG - PG;
        const int n = w >> 7;
        const int c = (w & 127) * 4;
        const int o = (n & 511) * 3 + (n >> 9);
        f4 v = *(const f4*)(Wk + (size_t)o * 512 + c);
        us4 ov; ov[0]=f2bf(v[0]); ov[1]=f2bf(v[1]); ov[2]=f2bf(v[2]); ov[3]=f2bf(v[3]);
        *(us4*)(wkb + (size_t)n * 512 + c) = ov;
    }
}

// ---- staging: one K-half panel = rows x 64B, linear in LDS, col-swizzled on global src.
// LDS[row][s] = G[row][s ^ ((row>>1)&3)]; reader XORs the same (involution). 0 conflicts (r2-r7).
template<int NINST>
__device__ __forceinline__ void stage_half(const char* base, int ld, char* dst, int tid) {
    #pragma unroll
    for (int inst = 0; inst < NINST; ++inst) {
        const int idx = inst * 512 + tid;
        const int row = idx >> 2;
        const int scol = ((idx & 3) ^ ((row >> 1) & 3)) << 4;
        __builtin_amdgcn_global_load_lds(
            (const AS1 void*)(base + (size_t)row * (size_t)ld + scol),
            (AS3 void*)(dst + (size_t)(inst * 512 + (tid & ~63)) * 16),
            16, 0, 0);
    }
}

// 256-thread variant (4 threads/row of 64B)
template<int NINST>
__device__ __forceinline__ void stage256(const char* base, int ld, char* dst, int tid) {
    #pragma unroll
    for (int inst = 0; inst < NINST; ++inst) {
        const int idx = inst * 256 + tid;
        const int row = idx >> 2;
        const int scol = ((idx & 3) ^ ((row >> 1) & 3)) << 4;
        __builtin_amdgcn_global_load_lds(
            (const AS1 void*)(base + (size_t)row * (size_t)ld + scol),
            (AS3 void*)(dst + (size_t)(inst * 256 + (tid & ~63)) * 16),
            16, 0, 0);
    }
}

// gemm2 cluster: 8 mi x 2 nj = 16 MFMA
#define CLUSTER16_G2(AF, BF, njb)                                            \
    __builtin_amdgcn_s_setprio(1);                                           \
    _Pragma("unroll")                                                        \
    for (int i_ = 0; i_ < 8; ++i_)                                           \
        _Pragma("unroll")                                                    \
        for (int j_ = 0; j_ < 2; ++j_)                                       \
            acc[i_][(njb) + j_] = __builtin_amdgcn_mfma_f32_16x16x32_bf16(   \
                AF[i_], BF[j_], acc[i_][(njb) + j_], 0, 0, 0);               \
    __builtin_amdgcn_s_setprio(0);                                           \
    SB0();

// gemm1: m97-style 128x128 tile, BK=32, 256 thr (4 waves 2x2), per-wave 64x64.
// LDS 2 x 16KB dbuf -> ~3 blocks/CU; cross-block implicit overlap hides stalls
// (m114/m97 mechanism). Simple 2-barrier loop, no setprio (m190).
__global__ __launch_bounds__(256, 3) void gemm1(const ushort_t* __restrict__ qb,
                                                const ushort_t* __restrict__ wkb,
                                                const float* __restrict__ bkp,
                                                ushort_t* __restrict__ coef) {
    __shared__ alignas(16) char lds[32768];    // [2][ A 8KB | B 8KB ]
    const int tid = threadIdx.x;
    const int l = tid & 63, wid = tid >> 6;
    const int wr = wid >> 1, wc = wid & 1;     // 2 x 2 wave grid
    int bid = blockIdx.x;
    bid = (bid & 7) * 192 + (bid >> 3);        // XCD swizzle, 1536 = 8*192
    const int mt = bid & 127, nt = bid >> 7;   // 128 m-tiles x 12 n-tiles
    const int mbase = mt * 128, nbase = nt * 128;

    const char* Ag = (const char*)(qb + (size_t)mbase * 512);
    const char* Bg = (const char*)(wkb + (size_t)nbase * 512);

    const int r15 = l & 15, q = l >> 4;
    const int swz = ((q ^ (r15 >> 1)) & 3) << 4;
    const int laneA = (wr * 64 + r15) * 64 + swz;
    const int laneB = (wc * 64 + r15) * 64 + swz;

    f32x4 acc[4][4];
    #pragma unroll
    for (int mi = 0; mi < 4; ++mi)
        #pragma unroll
        for (int ni = 0; ni < 4; ++ni)
            #pragma unroll
            for (int r = 0; r < 4; ++r) acc[mi][ni][r] = 0.f;

    // prologue: stage tile 0
    stage256<2>(Ag, 1024, lds, tid);
    stage256<2>(Bg, 1024, lds + 8192, tid);
    __syncthreads();

    for (int t = 0; t < 16; ++t) {
        const char* R = lds + ((t & 1) ? 16384 : 0);
        char* W       = lds + ((t & 1) ? 0 : 16384);
        const int tn = (t < 15) ? t + 1 : 15;

        // stage next tile (into the other buffer)
        stage256<2>(Ag + (size_t)tn * 64, 1024, W, tid);
        stage256<2>(Bg + (size_t)tn * 64, 1024, W + 8192, tid);

        // read current fragments and accumulate
        bf16x8 a[4], b[4];
        #pragma unroll
        for (int i = 0; i < 4; ++i) a[i] = *(const bf16x8*)(R + laneA + i * 1024);
        #pragma unroll
        for (int j = 0; j < 4; ++j) b[j] = *(const bf16x8*)(R + 8192 + laneB + j * 1024);
        #pragma unroll
        for (int i = 0; i < 4; ++i)
            #pragma unroll
            for (int j = 0; j < 4; ++j)
                acc[i][j] = __builtin_amdgcn_mfma_f32_16x16x32_bf16(a[i], b[j], acc[i][j], 0, 0, 0);
        __syncthreads();
    }

    #pragma unroll
    for (int ni = 0; ni < 4; ++ni) {
        const int ncol = nbase + wc * 64 + ni * 16 + r15;
        const float bkv = bkp[ncol];
        #pragma unroll
        for (int mi = 0; mi < 4; ++mi) {
            const int mrow0 = mbase + wr * 64 + mi * 16 + q * 4;
            #pragma unroll
            for (int r = 0; r < 4; ++r)
                coef[(size_t)(mrow0 + r) * 1536 + ncol] = f2bf(acc[mi][ni][r] + bkv);
        }
    }
}

// gemm2: 256x256 tile, BK=64, 8 waves (2x4), per-wave 128x64. LDS 2x64KB dbuf.
// Per buf: Ah0@0(16K) Ah1@16384 Bh0@32768 Bh1@49152.
// 4 phases/tile (kk x nj-half), 16 MFMA each, reads 10/2/10/2; stage one half per
// phase in need-order [Ah0,Bh0,Ah1,Bh1]; vmcnt(4) at P2 (t.h1 ready) and P4
// ((t+1).h0 ready). Unchanged from round 7 (known-good, 928 TF).
__global__ __launch_bounds__(512, 2) void gemm2(const ushort_t* __restrict__ coef,
                                                const ushort_t* __restrict__ kbp,
                                                const float* __restrict__ biasw,
                                                const float* __restrict__ bias_b,
                                                float* __restrict__ out) {
    __shared__ alignas(16) char lds[131072];
    const int tid = threadIdx.x;
    const int l = tid & 63, wid = tid >> 6;
    const int wr = wid >> 2, wc = wid & 3;
    int bid = blockIdx.x;
    bid = (bid & 7) * 32 + (bid >> 3);           // XCD swizzle, 256 = 8*32
    const int jt = bid & 3, it = (bid >> 2) & 3, b = bid >> 4;
    const int ibase = it * 256, jbase = jt * 256;

    const char* Ag = (const char*)(coef + ((size_t)b * 1024 + ibase) * 1536);
    const char* Bg = (const char*)(kbp + ((size_t)b * 1026 + jbase) * 512);

    const int r15 = l & 15, q = l >> 4;
    const int swz = ((q ^ (r15 >> 1)) & 3) << 4;
    const int laneA = (wr * 128 + r15) * 64 + swz;
    const int laneB = (wc * 64 + r15) * 64 + swz;

    f32x4 acc[8][4];
    #pragma unroll
    for (int mi = 0; mi < 8; ++mi)
        #pragma unroll
        for (int ni = 0; ni < 4; ++ni)
            #pragma unroll
            for (int r = 0; r < 4; ++r) acc[mi][ni][r] = 0.f;

    // prologue: stage tile 0 in need-order [Ah0,Bh0,Ah1,Bh1]; wait oldest 4
    stage_half<2>(Ag, 3072, lds, tid);
    stage_half<2>(Bg, 1024, lds + 32768, tid);
    stage_half<2>(Ag + 64, 3072, lds + 16384, tid);
    stage_half<2>(Bg + 64, 1024, lds + 49152, tid);
    VMCNT(4);
    SBAR(); SB0();

    for (int t = 0; t < 24; ++t) {
        const char* R = lds + ((t & 1) << 16);
        char* W       = lds + (((t + 1) & 1) << 16);
        const int tn = (t < 23) ? t + 1 : t;
        const size_t aoff = (size_t)tn * 128;
        const size_t boff = (size_t)(tn >> 3) * 1024 + (size_t)(tn & 7) * 128;

        bf16x8 A0[8], B0[2], B1[2];
        // ---- P1: kk0, nj 0-1 (reads 10); stage (t+1).Ah0
        #pragma unroll
        for (int i = 0; i < 8; ++i) A0[i] = *(const bf16x8*)(R + laneA + i * 1024);
        B0[0] = *(const bf16x8*)(R + 32768 + laneB);
        B0[1] = *(const bf16x8*)(R + 32768 + laneB + 1024);
        stage_half<2>(Ag + aoff, 3072, W, tid);
        SBAR();
        LGKM0_SB();
        CLUSTER16_G2(A0, B0, 0)

        // ---- P2: kk0, nj 2-3 (reads 2); stage (t+1).Bh0; vmcnt(4) -> t.h1 landed
        B1[0] = *(const bf16x8*)(R + 32768 + laneB + 2048);
        B1[1] = *(const bf16x8*)(R + 32768 + laneB + 3072);
        stage_half<2>(Bg + boff, 1024, W + 32768, tid);
        VMCNT(4);
        SBAR();
        LGKM0_SB();
        CLUSTER16_G2(A0, B1, 2)

        // ---- P3: kk1, nj 0-1 (reads 10); stage (t+1).Ah1
        #pragma unroll
        for (int i = 0; i < 8; ++i) A0[i] = *(const bf16x8*)(R + 16384 + laneA + i * 1024);
        B0[0] = *(const bf16x8*)(R + 49152 + laneB);
        B0[1] = *(const bf16x8*)(R + 49152 + laneB + 1024);
        stage_half<2>(Ag + aoff + 64, 3072, W + 16384, tid);
        SBAR();
        LGKM0_SB();
        CLUSTER16_G2(A0, B0, 0)

        // ---- P4: kk1, nj 2-3 (reads 2); stage (t+1).Bh1; vmcnt(4) -> (t+1).h0 landed
        B1[0] = *(const bf16x8*)(R + 49152 + laneB + 2048);
        B1[1] = *(const bf16x8*)(R + 49152 + laneB + 3072);
        stage_half<2>(Bg + boff + 64, 1024, W + 49152, tid);
        VMCNT(4);
        SBAR();
        LGKM0_SB();
        CLUSTER16_G2(A0, B1, 2)
    }

    const float bb0v = bias_b[0];
    #pragma unroll
    for (int mi = 0; mi < 8; ++mi) {
        const int irow0 = ibase + wr * 128 + mi * 16 + q * 4;
        #pragma unroll
        for (int r = 0; r < 4; ++r) {
            const float bv = biasw[b * 1024 + irow0 + r] + bb0v;
            #pragma unroll
            for (int ni = 0; ni < 4; ++ni) {
                const int jcol = jbase + wc * 64 + ni * 16 + r15;
                out[((size_t)b << 20) + (size_t)(irow0 + r) * 1024 + jcol] = acc[mi][ni][r] + bv;
            }
        }
    }
}

extern "C" void kernel_launch(void* const* d_in, const int* in_sizes, int n_in,
                              void* d_out, int out_size, void* d_ws, size_t ws_size,
                              hipStream_t stream) {
    const float* q      = (const float*)d_in[0];
    const float* k      = (const float*)d_in[1];
    const float* Wk     = (const float*)d_in[2];
    const float* bk     = (const float*)d_in[3];
    const float* Wb     = (const float*)d_in[4];
    const float* bb     = (const float*)d_in[5];
    const float* bias_b = (const float*)d_in[6];
    float* out = (float*)d_out;

    ushort_t* ws   = (ushort_t*)d_ws;
    ushort_t* qb   = ws;
    ushort_t* kbp  = qb  + (size_t)16384 * 512;
    ushort_t* wkb  = kbp + (size_t)16 * 1026 * 512;
    ushort_t* coef = wkb + (size_t)1536 * 512;
    float*    biasw = (float*)(coef + (size_t)16384 * 1536);
    float*    bkp   = biasw + 16384;

    prep_all<<<13072, 256, 0, stream>>>(q, Wb, bb, k, Wk, bk, qb, biasw, kbp, wkb, bkp);
    gemm1<<<1536, 256, 0, stream>>>(qb, wkb, bkp, coef);
    gemm2<<<256, 512, 0, stream>>>(coef, kbp, biasw, bias_b, out);
}

// Round 10
// 214.331 us; speedup vs baseline: 1.0190x; 1.0190x over previous
//
#include <hip/hip_runtime.h>

typedef unsigned short ushort_t;
typedef unsigned int uint32;
typedef __bf16 bf16x8 __attribute__((ext_vector_type(8)));
typedef float f32x4 __attribute__((ext_vector_type(4)));
typedef float f4 __attribute__((ext_vector_type(4)));
typedef unsigned short us4 __attribute__((ext_vector_type(4)));

// ---- constants for this problem shape ----
// B=16, QL=1024, KL=1024, QS=512, KS=512, KW=3, PAD=1
// gemm1: M=16384, N=1536, K=512   gemm2 (per b): M=1024, N=1024, K=1536 (3 shifted 512-segs)

__device__ __forceinline__ ushort_t f2bf(float f) {
    uint32 u = __builtin_bit_cast(uint32, f);
    u = (u + 0x7fffu + ((u >> 16) & 1u)) >> 16;  // RNE
    return (ushort_t)u;
}

#define SB0() __builtin_amdgcn_sched_barrier(0)
#define SBAR() __builtin_amdgcn_s_barrier()
#define VMCNT(n) asm volatile("s_waitcnt vmcnt(" #n ")" ::: "memory")
#define LGKM0_SB() do { asm volatile("s_waitcnt lgkmcnt(0)" ::: "memory"); SB0(); } while (0)

#define AS1 __attribute__((address_space(1)))
#define AS3 __attribute__((address_space(3)))

// ---------------- fused prep ----------------
__global__ __launch_bounds__(256) void prep_all(const float* __restrict__ q,
                                                const float* __restrict__ Wb,
                                                const float* __restrict__ bb,
                                                const float* __restrict__ k,
                                                const float* __restrict__ Wk,
                                                const float* __restrict__ bk,
                                                ushort_t* __restrict__ qb,
                                                float* __restrict__ biasw,
                                                ushort_t* __restrict__ kbp,
                                                ushort_t* __restrict__ wkb,
                                                float* __restrict__ bkp) {
    const int tid = threadIdx.x;
    if (blockIdx.x < 4096) {
        const int lane = tid & 63, wid = tid >> 6;
        const int m = blockIdx.x * 4 + wid;
        const float* qrow = q + (size_t)m * 512;

        f4 v0 = *(const f4*)(qrow + lane * 4);
        f4 v1 = *(const f4*)(qrow + 256 + lane * 4);
        f4 w0 = *(const f4*)(Wb + lane * 4);
        f4 w1 = *(const f4*)(Wb + 256 + lane * 4);

        float dot = v0[0]*w0[0] + v0[1]*w0[1] + v0[2]*w0[2] + v0[3]*w0[3]
                  + v1[0]*w1[0] + v1[1]*w1[1] + v1[2]*w1[2] + v1[3]*w1[3];

        us4 o0, o1;
        o0[0]=f2bf(v0[0]); o0[1]=f2bf(v0[1]); o0[2]=f2bf(v0[2]); o0[3]=f2bf(v0[3]);
        o1[0]=f2bf(v1[0]); o1[1]=f2bf(v1[1]); o1[2]=f2bf(v1[2]); o1[3]=f2bf(v1[3]);
        *(us4*)(qb + (size_t)m * 512 + lane * 4) = o0;
        *(us4*)(qb + (size_t)m * 512 + 256 + lane * 4) = o1;

        #pragma unroll
        for (int off = 32; off >= 1; off >>= 1) dot += __shfl_xor(dot, off);
        if (lane == 0) biasw[m] = dot + bb[0];
        return;
    }
    const int gid = (blockIdx.x - 4096) * 256 + tid;
    if (gid < 1536) bkp[gid] = bk[(gid & 511) * 3 + (gid >> 9)];

    const int KG = (16 * 1024 * 512) / 4;
    const int PG = (16 * 2 * 512) / 4;

    if (gid < KG) {
        const int e = gid * 4;
        const int b = e >> 19;
        const int rem = e & ((1 << 19) - 1);
        const int row = rem >> 9, c = rem & 511;
        f4 v = *(const f4*)(k + e);
        us4 o; o[0]=f2bf(v[0]); o[1]=f2bf(v[1]); o[2]=f2bf(v[2]); o[3]=f2bf(v[3]);
        *(us4*)(kbp + ((size_t)b * 1026 + row + 1) * 512 + c) = o;
    } else if (gid < KG + PG) {
        const int p = gid - KG;
        const int b = p >> 8, off = p & 255;
        const int row = (off < 128) ? 0 : 1025;
        const int c = (off & 127) * 4;
        us4 z; z[0]=0; z[1]=0; z[2]=0; z[3]=0;
        *(us4*)(kbp + ((size_t)b * 1026 + row) * 512 + c) = z;
    } else {
        const int w = gid - KG - PG;
        const int n = w >> 7;
        const int c = (w & 127) * 4;
        const int o = (n & 511) * 3 + (n >> 9);
        f4 v = *(const f4*)(Wk + (size_t)o * 512 + c);
        us4 ov; ov[0]=f2bf(v[0]); ov[1]=f2bf(v[1]); ov[2]=f2bf(v[2]); ov[3]=f2bf(v[3]);
        *(us4*)(wkb + (size_t)n * 512 + c) = ov;
    }
}

// ---- staging: one K-half panel = rows x 64B, linear in LDS, col-swizzled on global src.
// LDS[row][s] = G[row][s ^ ((row>>1)&3)]; reader XORs the same (involution). 0 conflicts (r2-r8).
template<int NINST>
__device__ __forceinline__ void stage_half(const char* base, int ld, char* dst, int tid) {
    #pragma unroll
    for (int inst = 0; inst < NINST; ++inst) {
        const int idx = inst * 512 + tid;
        const int row = idx >> 2;
        const int scol = ((idx & 3) ^ ((row >> 1) & 3)) << 4;
        __builtin_amdgcn_global_load_lds(
            (const AS1 void*)(base + (size_t)row * (size_t)ld + scol),
            (AS3 void*)(dst + (size_t)(inst * 512 + (tid & ~63)) * 16),
            16, 0, 0);
    }
}

// gemm1 cluster: 4 mi x 4 nj = 16 MFMA (r7 known-good form)
#define CLUSTER16_G1(AF, BF)                                                 \
    __builtin_amdgcn_s_setprio(1);                                           \
    _Pragma("unroll")                                                        \
    for (int i_ = 0; i_ < 4; ++i_)                                           \
        _Pragma("unroll")                                                    \
        for (int j_ = 0; j_ < 4; ++j_)                                       \
            acc[i_][j_] = __builtin_amdgcn_mfma_f32_16x16x32_bf16(           \
                AF[i_], BF[j_], acc[i_][j_], 0, 0, 0);                       \
    __builtin_amdgcn_s_setprio(0);                                           \
    SB0();

// gemm2 cluster: 4 mi x 4 nj = 16 MFMA on acc rows r0..r0+3, unpinned (compiler schedules)
#define CLUSTER16_G2(AF, BF, r0)                                             \
    __builtin_amdgcn_s_setprio(1);                                           \
    _Pragma("unroll")                                                        \
    for (int i_ = 0; i_ < 4; ++i_)                                           \
        _Pragma("unroll")                                                    \
        for (int j_ = 0; j_ < 4; ++j_)                                       \
            acc[(r0) + i_][j_] = __builtin_amdgcn_mfma_f32_16x16x32_bf16(    \
                AF[i_], BF[j_], acc[(r0) + i_][j_], 0, 0, 0);                \
    __builtin_amdgcn_s_setprio(0);

// gemm1: 128x256 tile, BK=64, 8 waves (2x4), per-wave 64x64. 3 LDS bufs x 48KB.
// (r7 known-good version, 768 blocks.)
__global__ __launch_bounds__(512, 2) void gemm1(const ushort_t* __restrict__ qb,
                                                const ushort_t* __restrict__ wkb,
                                                const float* __restrict__ bkp,
                                                ushort_t* __restrict__ coef) {
    __shared__ alignas(16) char lds[147456];
    const int tid = threadIdx.x;
    const int l = tid & 63, wid = tid >> 6;
    const int wr = wid >> 2, wc = wid & 3;       // 2 x 4 wave grid
    int bid = blockIdx.x;
    bid = (bid & 7) * 96 + (bid >> 3);           // XCD swizzle, 768 = 8*96
    const int mt = bid & 127, nt = bid >> 7;     // 128 m-tiles x 6 n-tiles
    const int mbase = mt * 128, nbase = nt * 256;

    const char* Ag = (const char*)(qb + (size_t)mbase * 512);
    const char* Bg = (const char*)(wkb + (size_t)nbase * 512);

    const int r15 = l & 15, q = l >> 4;
    const int swz = ((q ^ (r15 >> 1)) & 3) << 4;
    const int laneA = (wr * 64 + r15) * 64 + swz;
    const int laneB = (wc * 64 + r15) * 64 + swz;

    f32x4 acc[4][4];
    #pragma unroll
    for (int mi = 0; mi < 4; ++mi)
        #pragma unroll
        for (int ni = 0; ni < 4; ++ni)
            #pragma unroll
            for (int r = 0; r < 4; ++r) acc[mi][ni][r] = 0.f;

    stage_half<1>(Ag, 1024, lds, tid);
    stage_half<2>(Bg, 1024, lds + 16384, tid);
    stage_half<1>(Ag + 64, 1024, lds + 8192, tid);
    stage_half<2>(Bg + 64, 1024, lds + 32768, tid);
    stage_half<1>(Ag + 128, 1024, lds + 49152, tid);
    stage_half<2>(Bg + 128, 1024, lds + 49152 + 16384, tid);
    stage_half<1>(Ag + 192, 1024, lds + 49152 + 8192, tid);
    stage_half<2>(Bg + 192, 1024, lds + 49152 + 32768, tid);
    VMCNT(9);
    SBAR(); SB0();

    for (int t = 0; t < 8; ++t) {
        const char* R = lds + (t % 3) * 49152;
        char* W       = lds + ((t + 2) % 3) * 49152;
        const int tn2 = (t + 2 < 8) ? t + 2 : 7;
        const size_t off2 = (size_t)tn2 * 128;

        bf16x8 A0[4], B0[4];
        #pragma unroll
        for (int i = 0; i < 4; ++i) A0[i] = *(const bf16x8*)(R + laneA + i * 1024);
        #pragma unroll
        for (int j = 0; j < 4; ++j) B0[j] = *(const bf16x8*)(R + 16384 + laneB + j * 1024);
        stage_half<1>(Ag + off2, 1024, W, tid);
        stage_half<2>(Bg + off2, 1024, W + 16384, tid);
        VMCNT(9);
        SBAR();
        LGKM0_SB();
        CLUSTER16_G1(A0, B0)

        #pragma unroll
        for (int i = 0; i < 4; ++i) A0[i] = *(const bf16x8*)(R + 8192 + laneA + i * 1024);
        #pragma unroll
        for (int j = 0; j < 4; ++j) B0[j] = *(const bf16x8*)(R + 32768 + laneB + j * 1024);
        stage_half<1>(Ag + off2 + 64, 1024, W + 8192, tid);
        stage_half<2>(Bg + off2 + 64, 1024, W + 32768, tid);
        VMCNT(9);
        SBAR();
        LGKM0_SB();
        CLUSTER16_G1(A0, B0)
    }

    #pragma unroll
    for (int ni = 0; ni < 4; ++ni) {
        const int ncol = nbase + wc * 64 + ni * 16 + r15;
        const float bkv = bkp[ncol];
        #pragma unroll
        for (int mi = 0; mi < 4; ++mi) {
            const int mrow0 = mbase + wr * 64 + mi * 16 + q * 4;
            #pragma unroll
            for (int r = 0; r < 4; ++r)
                coef[(size_t)(mrow0 + r) * 1536 + ncol] = f2bf(acc[mi][ni][r] + bkv);
        }
    }
}

// gemm2: 256x256 tile, BK=64, 8 waves (2x4), per-wave 128x64. LDS 2x64KB dbuf.
// Per buf: Ak0@0(16K) Ak1@16384 Bk0@32768 Bk1@49152.
// 4 phases/K-tile (mi-half x kk), 16 MFMA each, reads 8/4/8/4 (B held across mi-halves);
// stages P1->Ak0' P2->Bk0' P3->Ak1' P4->Bk1'; ONLY 2 sync points per tile:
//   SP-B after P2 {vmcnt(4); barrier} -> this tile's k1 halves landed (3/2-phase lead)
//   SP-A after P4 {vmcnt(4); barrier} -> next tile's k0 halves landed (3/2-phase lead)
// No per-phase barriers/pins: waves de-sync between SPs so LDS reads of one wave
// overlap MFMA of another (r8 accounting: lockstep serialized 768 cyc LDS + 2483 MFMA).
__global__ __launch_bounds__(512, 2) void gemm2(const ushort_t* __restrict__ coef,
                                                const ushort_t* __restrict__ kbp,
                                                const float* __restrict__ biasw,
                                                const float* __restrict__ bias_b,
                                                float* __restrict__ out) {
    __shared__ alignas(16) char lds[131072];
    const int tid = threadIdx.x;
    const int l = tid & 63, wid = tid >> 6;
    const int wr = wid >> 2, wc = wid & 3;
    int bid = blockIdx.x;
    bid = (bid & 7) * 32 + (bid >> 3);           // XCD swizzle, 256 = 8*32
    const int jt = bid & 3, it = (bid >> 2) & 3, b = bid >> 4;
    const int ibase = it * 256, jbase = jt * 256;

    const char* Ag = (const char*)(coef + ((size_t)b * 1024 + ibase) * 1536);
    const char* Bg = (const char*)(kbp + ((size_t)b * 1026 + jbase) * 512);

    const int r15 = l & 15, q = l >> 4;
    const int swz = ((q ^ (r15 >> 1)) & 3) << 4;
    const int laneA = (wr * 128 + r15) * 64 + swz;
    const int laneB = (wc * 64 + r15) * 64 + swz;

    f32x4 acc[8][4];
    #pragma unroll
    for (int mi = 0; mi < 8; ++mi)
        #pragma unroll
        for (int ni = 0; ni < 4; ++ni)
            #pragma unroll
            for (int r = 0; r < 4; ++r) acc[mi][ni][r] = 0.f;

    // prologue: stage tile 0 in need-order [Ak0,Bk0,Ak1,Bk1]; wait oldest 4
    stage_half<2>(Ag, 3072, lds, tid);
    stage_half<2>(Bg, 1024, lds + 32768, tid);
    stage_half<2>(Ag + 64, 3072, lds + 16384, tid);
    stage_half<2>(Bg + 64, 1024, lds + 49152, tid);
    VMCNT(4);
    SBAR();

    for (int t = 0; t < 24; ++t) {
        const char* R = lds + ((t & 1) << 16);
        char* W       = lds + (((t + 1) & 1) << 16);
        const int tn = (t < 23) ? t + 1 : t;
        const size_t aoff = (size_t)tn * 128;
        const size_t boff = (size_t)(tn >> 3) * 1024 + (size_t)(tn & 7) * 128;

        bf16x8 A0[4], A1[4], B0[4], B1[4];
        // ---- P1: kk0, mi 0-3 (reads 8); stage Ak0(t+1)
        #pragma unroll
        for (int i = 0; i < 4; ++i) A0[i] = *(const bf16x8*)(R + laneA + i * 1024);
        #pragma unroll
        for (int j = 0; j < 4; ++j) B0[j] = *(const bf16x8*)(R + 32768 + laneB + j * 1024);
        stage_half<2>(Ag + aoff, 3072, W, tid);
        CLUSTER16_G2(A0, B0, 0)

        // ---- P2: kk0, mi 4-7 (reads 4, B held); stage Bk0(t+1); SP-B
        #pragma unroll
        for (int i = 0; i < 4; ++i) A1[i] = *(const bf16x8*)(R + laneA + (4 + i) * 1024);
        stage_half<2>(Bg + boff, 1024, W + 32768, tid);
        CLUSTER16_G2(A1, B0, 4)
        VMCNT(4);
        SBAR();

        // ---- P3: kk1, mi 0-3 (reads 8); stage Ak1(t+1)
        #pragma unroll
        for (int i = 0; i < 4; ++i) A0[i] = *(const bf16x8*)(R + 16384 + laneA + i * 1024);
        #pragma unroll
        for (int j = 0; j < 4; ++j) B1[j] = *(const bf16x8*)(R + 49152 + laneB + j * 1024);
        stage_half<2>(Ag + aoff + 64, 3072, W + 16384, tid);
        CLUSTER16_G2(A0, B1, 0)

        // ---- P4: kk1, mi 4-7 (reads 4, B held); stage Bk1(t+1); SP-A
        #pragma unroll
        for (int i = 0; i < 4; ++i) A1[i] = *(const bf16x8*)(R + 16384 + laneA + (4 + i) * 1024);
        stage_half<2>(Bg + boff + 64, 1024, W + 49152, tid);
        CLUSTER16_G2(A1, B1, 4)
        VMCNT(4);
        SBAR();
    }

    const float bb0v = bias_b[0];
    #pragma unroll
    for (int mi = 0; mi < 8; ++mi) {
        const int irow0 = ibase + wr * 128 + mi * 16 + q * 4;
        #pragma unroll
        for (int r = 0; r < 4; ++r) {
            const float bv = biasw[b * 1024 + irow0 + r] + bb0v;
            #pragma unroll
            for (int ni = 0; ni < 4; ++ni) {
                const int jcol = jbase + wc * 64 + ni * 16 + r15;
                out[((size_t)b << 20) + (size_t)(irow0 + r) * 1024 + jcol] = acc[mi][ni][r] + bv;
            }
        }
    }
}

extern "C" void kernel_launch(void* const* d_in, const int* in_sizes, int n_in,
                              void* d_out, int out_size, void* d_ws, size_t ws_size,
                              hipStream_t stream) {
    const float* q      = (const float*)d_in[0];
    const float* k      = (const float*)d_in[1];
    const float* Wk     = (const float*)d_in[2];
    const float* bk     = (const float*)d_in[3];
    const float* Wb     = (const float*)d_in[4];
    const float* bb     = (const float*)d_in[5];
    const float* bias_b = (const float*)d_in[6];
    float* out = (float*)d_out;

    ushort_t* ws   = (ushort_t*)d_ws;
    ushort_t* qb   = ws;
    ushort_t* kbp  = qb  + (size_t)16384 * 512;
    ushort_t* wkb  = kbp + (size_t)16 * 1026 * 512;
    ushort_t* coef = wkb + (size_t)1536 * 512;
    float*    biasw = (float*)(coef + (size_t)16384 * 1536);
    float*    bkp   = biasw + 16384;

    prep_all<<<13072, 256, 0, stream>>>(q, Wb, bb, k, Wk, bk, qb, biasw, kbp, wkb, bkp);
    gemm1<<<768, 512, 0, stream>>>(qb, wkb, bkp, coef);
    gemm2<<<256, 512, 0, stream>>>(coef, kbp, biasw, bias_b, out);
}